// Round 1
// baseline (2025.130 us; speedup 1.0000x reference)
//
#include <hip/hip_runtime.h>

// GCN encoder: L=3 GCNConv(64->64, leaky_relu 0.2) + latent GCNConv(64->32)
// + skip projections folded into the output accumulator.
// N=100k nodes, E=1.6M edges, f32 everywhere.

#define HID 64
#define LAT 32

static inline int cdiv(long long a, long long b) { return (int)((a + b - 1) / b); }

// ---------------- degree / normalization ----------------

__global__ void deg_init_kernel(float* __restrict__ deg, int n) {
    int v = blockIdx.x * blockDim.x + threadIdx.x;
    if (v < n) deg[v] = 1.0f;  // self loop
}

__global__ void deg_count_kernel(const int* __restrict__ dst, float* __restrict__ deg, int E) {
    int e = blockIdx.x * blockDim.x + threadIdx.x;
    if (e < E) atomicAdd(&deg[dst[e]], 1.0f);
}

__global__ void deg_finalize_kernel(float* __restrict__ deg, int n) {
    int v = blockIdx.x * blockDim.x + threadIdx.x;
    if (v < n) deg[v] = 1.0f / sqrtf(deg[v]);  // dinv
}

// ---------------- dense matmul (+bias), optional accumulate ----------------
// out[n x CO] (+)= in[n x CI] @ W[CI x CO] (+ bias)
// 256 threads/block, each thread owns one output element; W staged in LDS.

template <int CI, int CO, bool ACCUM>
__global__ void matmul_kernel(const float* __restrict__ in, const float* __restrict__ W,
                              const float* __restrict__ bias, float* __restrict__ out, int n) {
    __shared__ float Wl[CI * CO];
    for (int i = threadIdx.x; i < CI * CO; i += blockDim.x) Wl[i] = W[i];
    __syncthreads();

    constexpr int RPB = 256 / CO;  // rows per block
    int r = blockIdx.x * RPB + (int)(threadIdx.x / CO);
    int c = threadIdx.x % CO;
    if (r >= n) return;

    const float* row = in + (size_t)r * CI;
    float acc = bias ? bias[c] : 0.0f;
#pragma unroll 16
    for (int k = 0; k < CI; ++k) acc = fmaf(row[k], Wl[k * CO + c], acc);

    size_t o = (size_t)r * CO + c;
    if (ACCUM) out[o] += acc;
    else out[o] = acc;
}

// ---------------- self-loop init: acc[v] (+)= hw[v] * dinv[v]^2 ----------------

template <int CO, bool ACCUM>
__global__ void selfloop_kernel(const float* __restrict__ hw, const float* __restrict__ dinv,
                                float* __restrict__ acc, int n) {
    long long t = (long long)blockIdx.x * blockDim.x + threadIdx.x;
    if (t >= (long long)n * CO) return;
    int v = (int)(t / CO);
    float di = dinv[v];
    float val = hw[t] * di * di;
    if (ACCUM) acc[t] += val;
    else acc[t] = val;
}

// ---------------- edge scatter: acc[dst] += hw[src] * dinv[src]*dinv[dst] ----------------
// CO lanes per edge (64: one wave per edge; 32: two edges per wave).
// hw gather is a coalesced 256B/128B row read; atomics are contiguous per edge.

template <int CO>
__global__ void edge_scatter_kernel(const int* __restrict__ src, const int* __restrict__ dst,
                                    const float* __restrict__ dinv, const float* __restrict__ hw,
                                    float* acc, int E) {
    constexpr int SH = (CO == 64) ? 6 : 5;
    long long t = (long long)blockIdx.x * blockDim.x + threadIdx.x;
    long long e = t >> SH;
    int c = (int)(t & (CO - 1));
    if (e >= E) return;
    int s = src[e];
    int d = dst[e];
    float nrm = dinv[s] * dinv[d];
    atomicAdd(&acc[(size_t)d * CO + c], hw[(size_t)s * CO + c] * nrm);
}

// ---------------- epilogue: h_next = leaky_relu(acc + bias, 0.2) ----------------

__global__ void epilogue_kernel(const float* __restrict__ acc, const float* __restrict__ bias,
                                float* __restrict__ out, int n) {
    long long t = (long long)blockIdx.x * blockDim.x + threadIdx.x;
    if (t >= (long long)n * HID) return;
    int c = (int)(t & (HID - 1));
    float x = acc[t] + bias[c];
    out[t] = x > 0.0f ? x : 0.2f * x;
}

// ---------------- output init: d_out[v,c] = bl[c] + sum_i bs[i,c] ----------------

__global__ void out_init_kernel(const float* __restrict__ bl, const float* __restrict__ bs,
                                float* __restrict__ out, int n) {
    long long t = (long long)blockIdx.x * blockDim.x + threadIdx.x;
    if (t >= (long long)n * LAT) return;
    int c = (int)(t & (LAT - 1));
    out[t] = bl[c] + bs[c] + bs[LAT + c] + bs[2 * LAT + c];
}

// ---------------- launch ----------------

extern "C" void kernel_launch(void* const* d_in, const int* in_sizes, int n_in,
                              void* d_out, int out_size, void* d_ws, size_t ws_size,
                              hipStream_t stream) {
    const float* x    = (const float*)d_in[0];
    const int*   ei   = (const int*)d_in[1];
    const float* W_in = (const float*)d_in[2];
    const float* b_in = (const float*)d_in[3];
    const float* Wg   = (const float*)d_in[4];  // [3][64][64]
    const float* bg   = (const float*)d_in[5];  // [3][64]
    const float* Ws   = (const float*)d_in[6];  // [3][64][32]
    const float* bs   = (const float*)d_in[7];  // [3][32]
    const float* Wl   = (const float*)d_in[8];  // [64][32]
    const float* bl   = (const float*)d_in[9];  // [32]

    const int N = in_sizes[0] / 128;
    const int E = in_sizes[1] / 2;
    const int* srcp = ei;
    const int* dstp = ei + E;

    float* ws    = (float*)d_ws;
    float* dinv  = ws;                       // N
    float* hcur  = dinv + N;                 // N*64
    float* hnext = hcur + (size_t)N * HID;   // N*64
    float* hw    = hnext + (size_t)N * HID;  // N*64
    float* acc   = hw + (size_t)N * HID;     // N*64
    float* out   = (float*)d_out;            // N*32

    const int B = 256;

    // normalization
    deg_init_kernel<<<cdiv(N, B), B, 0, stream>>>(dinv, N);
    deg_count_kernel<<<cdiv(E, B), B, 0, stream>>>(dstp, dinv, E);
    deg_finalize_kernel<<<cdiv(N, B), B, 0, stream>>>(dinv, N);

    // input layer: hcur = x @ W_in + b_in
    matmul_kernel<128, HID, false><<<cdiv(N, 4), B, 0, stream>>>(x, W_in, b_in, hcur, N);

    // d_out starts with all output biases
    out_init_kernel<<<cdiv((long long)N * LAT, B), B, 0, stream>>>(bl, bs, out, N);

    for (int i = 0; i < 3; ++i) {
        // skip projection folded into output: out += hcur @ Ws[i]
        matmul_kernel<HID, LAT, true><<<cdiv(N, 8), B, 0, stream>>>(
            hcur, Ws + (size_t)i * HID * LAT, nullptr, out, N);

        // hw = hcur @ Wg[i]   (bias added in epilogue, after aggregation)
        matmul_kernel<HID, HID, false><<<cdiv(N, 4), B, 0, stream>>>(
            hcur, Wg + (size_t)i * HID * HID, nullptr, hw, N);

        // acc = self-loop term, then scatter edges
        selfloop_kernel<HID, false><<<cdiv((long long)N * HID, B), B, 0, stream>>>(hw, dinv, acc, N);
        edge_scatter_kernel<HID><<<cdiv((long long)E * HID, B), B, 0, stream>>>(
            srcp, dstp, dinv, hw, acc, E);

        // hnext = leaky_relu(acc + bg[i])
        epilogue_kernel<<<cdiv((long long)N * HID, B), B, 0, stream>>>(
            acc, bg + (size_t)i * HID, hnext, N);

        float* tmp = hcur; hcur = hnext; hnext = tmp;
    }

    // latent GCN: hw32 = hcur @ Wl ; out += selfloop + edge scatter
    matmul_kernel<HID, LAT, false><<<cdiv(N, 8), B, 0, stream>>>(hcur, Wl, nullptr, hw, N);
    selfloop_kernel<LAT, true><<<cdiv((long long)N * LAT, B), B, 0, stream>>>(hw, dinv, out, N);
    edge_scatter_kernel<LAT><<<cdiv((long long)E * LAT, B), B, 0, stream>>>(
        srcp, dstp, dinv, hw, out, E);
}

// Round 2
// 1024.690 us; speedup vs baseline: 1.9763x; 1.9763x over previous
//
#include <hip/hip_runtime.h>

// GCN encoder, gather formulation.
// Per launch: build by-dst CSR (counts -> scan -> fill), then
//   h = x@W_in+b_in
//   for i in 0..2: out += h@Ws[i];  hw' = (h@Wg[i])*dinv;  h = lrelu(dinv*(hw'[v]+sum_nbr hw') + bg[i])
//   out += dinv*(hw'l[v]+sum hw'l)  with hw'l = (h@Wl)*dinv;  out pre-init with bl+sum(bs).

#define HID 64
#define LAT 32

static inline int cdiv(long long a, long long b) { return (int)((a + b - 1) / b); }

// ---------------- CSR build ----------------

__global__ void zero_counts_kernel(int* __restrict__ counts, int n) {
    int v = blockIdx.x * blockDim.x + threadIdx.x;
    if (v < n) counts[v] = 0;
}

__global__ void count_kernel(const int* __restrict__ dst, int* __restrict__ counts, int E) {
    int e = blockIdx.x * blockDim.x + threadIdx.x;
    if (e < E) atomicAdd(&counts[dst[e]], 1);
}

__global__ void dinv_kernel(const int* __restrict__ counts, float* __restrict__ dinv, int n) {
    int v = blockIdx.x * blockDim.x + threadIdx.x;
    if (v < n) dinv[v] = rsqrtf((float)(counts[v] + 1));  // +1 self loop
}

// exclusive scan, 2-level (n <= 512*256)
__global__ void scanA_kernel(const int* __restrict__ counts, int* __restrict__ rowstart,
                             int* __restrict__ bsum, int n) {
    __shared__ int s[256];
    int t = threadIdx.x;
    int i = blockIdx.x * 256 + t;
    int v = (i < n) ? counts[i] : 0;
    s[t] = v;
    __syncthreads();
    for (int off = 1; off < 256; off <<= 1) {
        int x = (t >= off) ? s[t - off] : 0;
        __syncthreads();
        s[t] += x;
        __syncthreads();
    }
    if (i < n) rowstart[i] = s[t] - v;  // exclusive within block
    if (t == 255) bsum[blockIdx.x] = s[255];
}

__global__ void scanB_kernel(int* __restrict__ bsum, int nb) {
    __shared__ int s[512];
    int t = threadIdx.x;
    int v = (t < nb) ? bsum[t] : 0;
    s[t] = v;
    __syncthreads();
    for (int off = 1; off < 512; off <<= 1) {
        int x = (t >= off) ? s[t - off] : 0;
        __syncthreads();
        s[t] += x;
        __syncthreads();
    }
    if (t < nb) bsum[t] = s[t] - v;  // exclusive block offsets
}

__global__ void scanC_kernel(int* __restrict__ rowstart, int* __restrict__ cursor,
                             const int* __restrict__ bsum, int n, int E) {
    int i = blockIdx.x * blockDim.x + threadIdx.x;
    if (i < n) {
        int r = rowstart[i] + bsum[blockIdx.x * (int)blockDim.x / 256 * 256 / 256];  // bsum[block of 256]
        // NOTE: blockDim.x == 256 so this is bsum[blockIdx.x]
        r = rowstart[i] + bsum[blockIdx.x];
        rowstart[i] = r;
        cursor[i] = r;
    }
    if (i == 0) rowstart[n] = E;
}

__global__ void fill_kernel(const int* __restrict__ src, const int* __restrict__ dst,
                            int* __restrict__ cursor, int* __restrict__ csr, int E) {
    int e = blockIdx.x * blockDim.x + threadIdx.x;
    if (e < E) {
        int pos = atomicAdd(&cursor[dst[e]], 1);
        csr[pos] = src[e];
    }
}

// ---------------- dense matmul (+bias), optional accumulate / dinv scale ----------------
// out[n x CO] (+)= (in[n x CI] @ W[CI x CO] (+ bias)) (* dinv[r])
// 256 threads, RPB=256/CO rows per block. W and the block's rows staged in LDS.

template <int CI, int CO, bool ACCUM, bool SCALE>
__global__ void matmul_kernel(const float* __restrict__ in, const float* __restrict__ W,
                              const float* __restrict__ bias, const float* __restrict__ dinv,
                              float* __restrict__ out, int n) {
    constexpr int RPB = 256 / CO;
    __shared__ float Wl[CI * CO];
    __shared__ float rows[RPB * CI];
    for (int i = threadIdx.x; i < CI * CO; i += 256) Wl[i] = W[i];
    // coalesced row staging: RPB*CI floats, contiguous from in
    long long base = (long long)blockIdx.x * RPB * CI;
    for (int i = threadIdx.x; i < RPB * CI; i += 256) {
        long long g = base + i;
        rows[i] = (g < (long long)n * CI) ? in[g] : 0.0f;
    }
    __syncthreads();

    int lr = threadIdx.x / CO;
    int r = blockIdx.x * RPB + lr;
    int c = threadIdx.x % CO;
    if (r >= n) return;

    const float* row = rows + lr * CI;
    float acc = bias ? bias[c] : 0.0f;
#pragma unroll 16
    for (int k = 0; k < CI; ++k) acc = fmaf(row[k], Wl[k * CO + c], acc);
    if (SCALE) acc *= dinv[r];

    size_t o = (size_t)r * CO + c;
    if (ACCUM) out[o] += acc;
    else out[o] = acc;
}

// ---------------- gather aggregate ----------------
// res[v] = dinv[v] * (hws[v] + sum_{s in nbr(v)} hws[s]) + bias  ; optional lrelu ; optional +=
// CO lanes per node; hws is pre-scaled by dinv (so self term needs no extra factor).

template <int CO, bool RELU, bool ACCUM>
__global__ void gather_kernel(const int* __restrict__ rowstart, const int* __restrict__ csr,
                              const float* __restrict__ dinv, const float* __restrict__ hws,
                              const float* __restrict__ bias, float* __restrict__ out, int n) {
    constexpr int NPB = 256 / CO;
    int node = blockIdx.x * NPB + (int)(threadIdx.x / CO);
    int c = threadIdx.x & (CO - 1);
    if (node >= n) return;

    int beg = rowstart[node];
    int end = rowstart[node + 1];
    float acc = hws[(size_t)node * CO + c];  // self (scaled)
    int e = beg;
    // unroll-by-2 to give the scheduler two independent load chains
    for (; e + 1 < end; e += 2) {
        int s0 = csr[e];
        int s1 = csr[e + 1];
        float v0 = hws[(size_t)s0 * CO + c];
        float v1 = hws[(size_t)s1 * CO + c];
        acc += v0 + v1;
    }
    if (e < end) acc += hws[(size_t)csr[e] * CO + c];

    float r = dinv[node] * acc + (bias ? bias[c] : 0.0f);
    if (RELU) r = r > 0.0f ? r : 0.2f * r;
    size_t o = (size_t)node * CO + c;
    if (ACCUM) out[o] += r;
    else out[o] = r;
}

// ---------------- output init: d_out[v,c] = bl[c] + sum_i bs[i,c] ----------------

__global__ void out_init_kernel(const float* __restrict__ bl, const float* __restrict__ bs,
                                float* __restrict__ out, int n) {
    long long t = (long long)blockIdx.x * blockDim.x + threadIdx.x;
    if (t >= (long long)n * LAT) return;
    int c = (int)(t & (LAT - 1));
    out[t] = bl[c] + bs[c] + bs[LAT + c] + bs[2 * LAT + c];
}

// ---------------- launch ----------------

extern "C" void kernel_launch(void* const* d_in, const int* in_sizes, int n_in,
                              void* d_out, int out_size, void* d_ws, size_t ws_size,
                              hipStream_t stream) {
    const float* x    = (const float*)d_in[0];
    const int*   ei   = (const int*)d_in[1];
    const float* W_in = (const float*)d_in[2];
    const float* b_in = (const float*)d_in[3];
    const float* Wg   = (const float*)d_in[4];  // [3][64][64]
    const float* bg   = (const float*)d_in[5];  // [3][64]
    const float* Ws   = (const float*)d_in[6];  // [3][64][32]
    const float* bs   = (const float*)d_in[7];  // [3][32]
    const float* Wl   = (const float*)d_in[8];  // [64][32]
    const float* bl   = (const float*)d_in[9];  // [32]

    const int N = in_sizes[0] / 128;
    const int E = in_sizes[1] / 2;
    const int* srcp = ei;
    const int* dstp = ei + E;

    // workspace layout (floats/ints are both 4B)
    char* p = (char*)d_ws;
    float* dinv     = (float*)p; p += (size_t)N * 4;
    int*   counts   = (int*)p;   p += (size_t)N * 4;
    int*   rowstart = (int*)p;   p += ((size_t)N + 1) * 4;
    int*   cursor   = (int*)p;   p += (size_t)N * 4;
    int*   bsum     = (int*)p;   p += 512 * 4;
    int*   csr      = (int*)p;   p += (size_t)E * 4;
    float* hcur     = (float*)p; p += (size_t)N * HID * 4;
    float* hnext    = (float*)p; p += (size_t)N * HID * 4;
    float* hw       = (float*)p; p += (size_t)N * HID * 4;
    float* out      = (float*)d_out;

    const int B = 256;
    const int nb = cdiv(N, 256);

    // --- CSR build + normalization ---
    zero_counts_kernel<<<cdiv(N, B), B, 0, stream>>>(counts, N);
    count_kernel<<<cdiv(E, B), B, 0, stream>>>(dstp, counts, E);
    dinv_kernel<<<cdiv(N, B), B, 0, stream>>>(counts, dinv, N);
    scanA_kernel<<<nb, 256, 0, stream>>>(counts, rowstart, bsum, N);
    scanB_kernel<<<1, 512, 0, stream>>>(bsum, nb);
    scanC_kernel<<<nb, 256, 0, stream>>>(rowstart, cursor, bsum, N, E);
    fill_kernel<<<cdiv(E, B), B, 0, stream>>>(srcp, dstp, cursor, csr, E);

    // --- input layer: hcur = x @ W_in + b_in ---
    matmul_kernel<128, HID, false, false><<<cdiv(N, 4), B, 0, stream>>>(
        x, W_in, b_in, nullptr, hcur, N);

    // --- d_out starts with all output biases ---
    out_init_kernel<<<cdiv((long long)N * LAT, B), B, 0, stream>>>(bl, bs, out, N);

    for (int i = 0; i < 3; ++i) {
        // skip projection folded into output: out += hcur @ Ws[i]
        matmul_kernel<HID, LAT, true, false><<<cdiv(N, 8), B, 0, stream>>>(
            hcur, Ws + (size_t)i * HID * LAT, nullptr, nullptr, out, N);

        // hw' = (hcur @ Wg[i]) * dinv   (bias added after aggregation)
        matmul_kernel<HID, HID, false, true><<<cdiv(N, 4), B, 0, stream>>>(
            hcur, Wg + (size_t)i * HID * HID, nullptr, dinv, hw, N);

        // hnext = lrelu(dinv*(hw'[v] + sum_nbr hw') + bg[i])
        gather_kernel<HID, true, false><<<cdiv(N, 4), B, 0, stream>>>(
            rowstart, csr, dinv, hw, bg + (size_t)i * HID, hnext, N);

        float* tmp = hcur; hcur = hnext; hnext = tmp;
    }

    // --- latent GCN: hw'l = (hcur @ Wl) * dinv ; out += dinv*(self + sum) ---
    matmul_kernel<HID, LAT, false, true><<<cdiv(N, 8), B, 0, stream>>>(
        hcur, Wl, nullptr, dinv, hw, N);
    gather_kernel<LAT, false, true><<<cdiv(N, 8), B, 0, stream>>>(
        rowstart, csr, dinv, hw, nullptr, out, N);
}